// Round 2
// baseline (62.580 us; speedup 1.0000x reference)
//
#include <hip/hip_runtime.h>

// Cox NLL over N=16384, two-phase multi-CU scan.
//   risk[i] = cumsum(exp(pred))[i]  (inclusive)
//   cost = -(sum((pred - log(risk)) * yevent) / max(sum(yevent), 1))
//
// K1: 64 blocks x 256 thr -> per-chunk sum of exp(pred) into ws[0..63]
// K2: 64 blocks x 256 thr -> every block re-scans the 64 chunk sums in one
//     wave (cheaper than a third launch), block-scans its own 256 exps,
//     computes masked sums, atomicAdds partials; last block (ticket) writes out.
//
// ws layout (floats): [0..63] chunk sums | [64] sd acc | [65] se acc | [66] ticket(int)

#define NLL_N      16384
#define NLL_CHUNKS 64
#define NLL_T      256

__global__ __launch_bounds__(NLL_T) void nll_k1(const float* __restrict__ pred,
                                                float* __restrict__ ws) {
    const int tid  = threadIdx.x;
    const int lane = tid & 63;
    const int wave = tid >> 6;                 // 0..3
    const int i    = blockIdx.x * NLL_T + tid;

    float e = __expf(pred[i]);
    #pragma unroll
    for (int off = 32; off > 0; off >>= 1) e += __shfl_down(e, off, 64);

    __shared__ float s[4];
    if (lane == 0) s[wave] = e;
    __syncthreads();
    if (tid == 0) ws[blockIdx.x] = s[0] + s[1] + s[2] + s[3];
}

__global__ __launch_bounds__(NLL_T) void nll_k2(const float* __restrict__ pred,
                                                const float* __restrict__ label,
                                                float* __restrict__ ws,
                                                float* __restrict__ out) {
    const int tid  = threadIdx.x;
    const int lane = tid & 63;
    const int wave = tid >> 6;                 // 0..3
    const int blk  = blockIdx.x;               // 0..63
    const int i    = blk * NLL_T + tid;

    __shared__ float exc[NLL_CHUNKS];          // exclusive chunk bases
    __shared__ float wt[4];                    // wave totals of this block's scan
    __shared__ float rd[4], re[4];             // reduction scratch

    // ---- wave 0: scan the 64 chunk sums (all 64 lanes active) ----
    if (wave == 0) {
        float own = ws[lane];
        float inc0 = own;
        #pragma unroll
        for (int off = 1; off < 64; off <<= 1) {
            float t = __shfl_up(inc0, off, 64);
            if (lane >= off) inc0 += t;
        }
        exc[lane] = inc0 - own;                // exclusive prefix of chunk `lane`
    }

    // ---- per-thread element, block-level inclusive scan of exp ----
    float p  = pred[i];
    float ev = ((const float2*)label)[i].y;    // yevent
    float e  = __expf(p);

    float inc = e;
    #pragma unroll
    for (int off = 1; off < 64; off <<= 1) {
        float t = __shfl_up(inc, off, 64);
        if (lane >= off) inc += t;
    }
    if (lane == 63) wt[wave] = inc;
    __syncthreads();

    float base = exc[blk];
    #pragma unroll
    for (int w = 0; w < 4; ++w) if (w < wave) base += wt[w];

    float risk = base + inc;                   // inclusive cumsum at row i
    float sd = ev * (p - __logf(risk));
    float se = ev;

    // ---- block reduction ----
    #pragma unroll
    for (int off = 32; off > 0; off >>= 1) {
        sd += __shfl_down(sd, off, 64);
        se += __shfl_down(se, off, 64);
    }
    if (lane == 0) { rd[wave] = sd; re[wave] = se; }
    __syncthreads();

    if (tid == 0) {
        float bsd = rd[0] + rd[1] + rd[2] + rd[3];
        float bse = re[0] + re[1] + re[2] + re[3];
        atomicAdd(&ws[64], bsd);
        atomicAdd(&ws[65], bse);
        __threadfence();
        unsigned old = atomicAdd((unsigned*)&ws[66], 1u);
        if (old == NLL_CHUNKS - 1) {           // last block finalizes
            __threadfence();
            float d = atomicAdd(&ws[64], 0.0f);
            float e2 = atomicAdd(&ws[65], 0.0f);
            out[1] = e2;
            out[0] = (e2 == 0.f) ? 0.f : -(d / fmaxf(e2, 1.f));
        }
    }
}

extern "C" void kernel_launch(void* const* d_in, const int* in_sizes, int n_in,
                              void* d_out, int out_size, void* d_ws, size_t ws_size,
                              hipStream_t stream) {
    const float* pred  = (const float*)d_in[0];   // (N,1) float32
    const float* label = (const float*)d_in[1];   // (N,2) float32
    float* out = (float*)d_out;                   // [cost, n_observed]
    float* ws  = (float*)d_ws;
    (void)in_sizes; (void)n_in; (void)out_size; (void)ws_size;

    // zero the accumulators + ticket (ws is poisoned 0xAA before every call)
    hipMemsetAsync((char*)d_ws + 64 * sizeof(float), 0, 3 * sizeof(float), stream);
    nll_k1<<<NLL_CHUNKS, NLL_T, 0, stream>>>(pred, ws);
    nll_k2<<<NLL_CHUNKS, NLL_T, 0, stream>>>(pred, label, ws, out);
}

// Round 3
// 60.959 us; speedup vs baseline: 1.0266x; 1.0266x over previous
//
#include <hip/hip_runtime.h>

// Cox NLL over N=16384, SINGLE kernel, flag-based grid sync (poison-tolerant).
//   risk[i] = cumsum(exp(pred))[i]  (inclusive)
//   cost = -(sum((pred - log(risk)) * yevent) / max(sum(yevent), 1))
//
// 64 blocks x 256 threads (grid << 256 CUs -> all co-resident).
// ws floats: [0..63] chunkSum | [64..127] flagA | [128..191] sdPart
//            | [192..255] sePart | [256..319] flagB
// Flags use magic 1.0f (poison 0xAAAAAAAA -> -3e-13, != 1.0f), so no memset
// is needed. All cross-block traffic uses agent-scope atomics (G16).

#define NLL_T      256
#define NLL_CHUNKS 64
#define NLL_MAGIC  1.0f

__device__ __forceinline__ float agent_load(const float* p) {
    return __hip_atomic_load(p, __ATOMIC_RELAXED, __HIP_MEMORY_SCOPE_AGENT);
}
__device__ __forceinline__ void agent_store(float* p, float v) {
    __hip_atomic_store(p, v, __ATOMIC_RELAXED, __HIP_MEMORY_SCOPE_AGENT);
}

__global__ __launch_bounds__(NLL_T) void nll_fused(const float* __restrict__ pred,
                                                   const float* __restrict__ label,
                                                   float* __restrict__ ws,
                                                   float* __restrict__ out) {
    const int tid  = threadIdx.x;
    const int lane = tid & 63;
    const int wave = tid >> 6;                 // 0..3
    const int blk  = blockIdx.x;               // 0..63
    const int i    = blk * NLL_T + tid;

    float* chunkSum = ws;
    float* flagA    = ws + 64;
    float* sdPart   = ws + 128;
    float* sePart   = ws + 192;
    float* flagB    = ws + 256;

    __shared__ float wt[4];                    // wave totals
    __shared__ float sb[1];                    // chunk base
    __shared__ float rd[4], re[4];             // reduction scratch

    // ---- load + exp + wave-level inclusive scan ----
    float p  = pred[i];
    float ev = ((const float2*)label)[i].y;    // yevent
    float e  = __expf(p);

    float inc = e;
    #pragma unroll
    for (int off = 1; off < 64; off <<= 1) {
        float t = __shfl_up(inc, off, 64);
        if (lane >= off) inc += t;
    }
    if (lane == 63) wt[wave] = inc;
    __syncthreads();

    // ---- publish this block's total exp-sum ----
    if (tid == 0) {
        float total = wt[0] + wt[1] + wt[2] + wt[3];
        agent_store(&chunkSum[blk], total);
        __threadfence();                       // order chunkSum before flagA
        agent_store(&flagA[blk], NLL_MAGIC);
    }

    // ---- wave 0: wait for all chunk sums, compute exclusive base for blk ----
    if (wave == 0) {
        while (!__all(agent_load(&flagA[lane]) == NLL_MAGIC)) {
            __builtin_amdgcn_s_sleep(1);
        }
        float s = (lane < blk) ? agent_load(&chunkSum[lane]) : 0.f;
        #pragma unroll
        for (int off = 32; off > 0; off >>= 1) s += __shfl_down(s, off, 64);
        if (lane == 0) sb[0] = s;
    }
    __syncthreads();

    // ---- risk + fused masked sums ----
    float base = sb[0];
    #pragma unroll
    for (int w = 0; w < 4; ++w) if (w < wave) base += wt[w];

    float risk = base + inc;                   // inclusive cumsum at row i
    float sd = ev * (p - __logf(risk));
    float se = ev;

    #pragma unroll
    for (int off = 32; off > 0; off >>= 1) {
        sd += __shfl_down(sd, off, 64);
        se += __shfl_down(se, off, 64);
    }
    if (lane == 0) { rd[wave] = sd; re[wave] = se; }
    __syncthreads();

    // ---- publish block partials ----
    if (tid == 0) {
        agent_store(&sdPart[blk], rd[0] + rd[1] + rd[2] + rd[3]);
        agent_store(&sePart[blk], re[0] + re[1] + re[2] + re[3]);
        __threadfence();
        agent_store(&flagB[blk], NLL_MAGIC);
    }

    // ---- block 0 finalizes ----
    if (blk == 0 && wave == 0) {
        while (!__all(agent_load(&flagB[lane]) == NLL_MAGIC)) {
            __builtin_amdgcn_s_sleep(1);
        }
        float d = agent_load(&sdPart[lane]);
        float n = agent_load(&sePart[lane]);
        #pragma unroll
        for (int off = 32; off > 0; off >>= 1) {
            d += __shfl_down(d, off, 64);
            n += __shfl_down(n, off, 64);
        }
        if (lane == 0) {
            out[1] = n;                                       // n_observed
            out[0] = (n == 0.f) ? 0.f : -(d / fmaxf(n, 1.f)); // cost
        }
    }
}

extern "C" void kernel_launch(void* const* d_in, const int* in_sizes, int n_in,
                              void* d_out, int out_size, void* d_ws, size_t ws_size,
                              hipStream_t stream) {
    const float* pred  = (const float*)d_in[0];   // (N,1) float32
    const float* label = (const float*)d_in[1];   // (N,2) float32
    float* out = (float*)d_out;                   // [cost, n_observed]
    float* ws  = (float*)d_ws;
    (void)in_sizes; (void)n_in; (void)out_size; (void)ws_size;
    nll_fused<<<NLL_CHUNKS, NLL_T, 0, stream>>>(pred, label, ws, out);
}